// Round 1
// baseline (2312.573 us; speedup 1.0000x reference)
//
#include <hip/hip_runtime.h>

#define B_ 32
#define T_ 4096
#define D_ 64
#define H_ 128
#define S_ 64
#define BTS (B_*T_*S_)   /* 8388608 */

// workspace float offsets
#define EM_OFF    0
#define BETA_OFF  BTS
#define P_OFF     (2*BTS)
#define PT_OFF    (2*BTS + 4096)
#define INITP_OFF (2*BTS + 8192)
// output float offsets
#define SP_OFF   0
#define MARG_OFF BTS
#define DUR_OFF  (BTS + 2048)
#define LL_OFF   (BTS + 2112)

__device__ __forceinline__ float wsum(float v) {
    #pragma unroll
    for (int m = 1; m < 64; m <<= 1) v += __shfl_xor(v, m, 64);
    return v;
}
__device__ __forceinline__ float wmax(float v) {
    #pragma unroll
    for (int m = 1; m < 64; m <<= 1) v = fmaxf(v, __shfl_xor(v, m, 64));
    return v;
}
__device__ __forceinline__ float rlane(float v, int k) {
    return __int_as_float(__builtin_amdgcn_readlane(__float_as_int(v), k));
}

// ---------------- Kernel A: prep (trans probs, init probs, durations, zero marginals)
__global__ __launch_bounds__(256) void prep_k(const float* __restrict__ LT,
                                              const float* __restrict__ lip,
                                              const float* __restrict__ logr,
                                              const float* __restrict__ logitp,
                                              float* __restrict__ ws,
                                              float* __restrict__ out) {
    int tid = threadIdx.x, wid = tid >> 6, lane = tid & 63;
    // transition matrix: masked softmax rows + EPS
    for (int r = wid; r < S_; r += 4) {
        float x = (lane == r) ? -1e10f : LT[r * S_ + lane];
        float m = wmax(x);
        float e = __expf(x - m);
        float s = wsum(e);
        float p = e / s + 1e-10f;
        ws[P_OFF  + r * S_ + lane] = p;
        ws[PT_OFF + lane * S_ + r] = p;
    }
    if (wid == 0) {
        float x = lip[lane];
        float m = wmax(x);
        float e = __expf(x - m);
        float s = wsum(e);
        ws[INITP_OFF + lane] = e / s;
    } else if (wid == 1) {
        float r = __expf(logr[lane]);
        float p = 1.f / (1.f + __expf(-logitp[lane]));
        out[DUR_OFF + lane] = r * (1.f - p) / p;
    }
    for (int i = tid; i < B_ * S_; i += 256) out[MARG_OFF + i] = 0.f;
}

// ---------------- Kernel B: emission MLP + softmax -> em (B,T,S) fp32
__global__ __launch_bounds__(256) void mlp_k(const float* __restrict__ obs,
                                             const float* __restrict__ W1, const float* __restrict__ b1,
                                             const float* __restrict__ W2, const float* __restrict__ b2,
                                             const float* __restrict__ W3, const float* __restrict__ b3,
                                             float* __restrict__ em) {
    __shared__ float sc[5120];          // xT[64][16] | h1T[128][16] | h2T[128][16]
    float* xT  = sc;
    float* h1T = sc + 1024;
    float* h2T = sc + 3072;
    int tid = threadIdx.x, wid = tid >> 6, lane = tid & 63;
    const float2* W1v = (const float2*)W1;
    const float2* W2v = (const float2*)W2;
    float2 b1v = ((const float2*)b1)[lane];
    float2 b2v = ((const float2*)b2)[lane];
    float  b3v = b3[lane];
    const int col = wid * 4;

    for (int c = blockIdx.x; c < (B_ * T_) / 16; c += gridDim.x) {
        int r0 = c * 16 + wid * 4;
        float4 xv;
        xv.x = obs[(size_t)(r0 + 0) * D_ + lane];
        xv.y = obs[(size_t)(r0 + 1) * D_ + lane];
        xv.z = obs[(size_t)(r0 + 2) * D_ + lane];
        xv.w = obs[(size_t)(r0 + 3) * D_ + lane];
        __syncthreads();                       // prev-chunk LDS reads done
        *(float4*)&xT[lane * 16 + col] = xv;
        __syncthreads();

        float h00=0,h01=0,h10=0,h11=0,h20=0,h21=0,h30=0,h31=0;
        #pragma unroll
        for (int d = 0; d < D_; d++) {
            float4 x4 = *(const float4*)&xT[d * 16 + col];
            float2 w  = W1v[d * 64 + lane];
            h00 = fmaf(x4.x, w.x, h00); h01 = fmaf(x4.x, w.y, h01);
            h10 = fmaf(x4.y, w.x, h10); h11 = fmaf(x4.y, w.y, h11);
            h20 = fmaf(x4.z, w.x, h20); h21 = fmaf(x4.z, w.y, h21);
            h30 = fmaf(x4.w, w.x, h30); h31 = fmaf(x4.w, w.y, h31);
        }
        h00 = fmaxf(h00 + b1v.x, 0.f); h01 = fmaxf(h01 + b1v.y, 0.f);
        h10 = fmaxf(h10 + b1v.x, 0.f); h11 = fmaxf(h11 + b1v.y, 0.f);
        h20 = fmaxf(h20 + b1v.x, 0.f); h21 = fmaxf(h21 + b1v.y, 0.f);
        h30 = fmaxf(h30 + b1v.x, 0.f); h31 = fmaxf(h31 + b1v.y, 0.f);
        float4 p0 = {h00, h10, h20, h30};
        float4 p1 = {h01, h11, h21, h31};
        *(float4*)&h1T[(2 * lane    ) * 16 + col] = p0;
        *(float4*)&h1T[(2 * lane + 1) * 16 + col] = p1;
        __syncthreads();

        float g00=0,g01=0,g10=0,g11=0,g20=0,g21=0,g30=0,g31=0;
        #pragma unroll
        for (int k = 0; k < H_; k++) {
            float4 h4 = *(const float4*)&h1T[k * 16 + col];
            float2 w  = W2v[k * 64 + lane];
            g00 = fmaf(h4.x, w.x, g00); g01 = fmaf(h4.x, w.y, g01);
            g10 = fmaf(h4.y, w.x, g10); g11 = fmaf(h4.y, w.y, g11);
            g20 = fmaf(h4.z, w.x, g20); g21 = fmaf(h4.z, w.y, g21);
            g30 = fmaf(h4.w, w.x, g30); g31 = fmaf(h4.w, w.y, g31);
        }
        g00 = fmaxf(g00 + b2v.x, 0.f); g01 = fmaxf(g01 + b2v.y, 0.f);
        g10 = fmaxf(g10 + b2v.x, 0.f); g11 = fmaxf(g11 + b2v.y, 0.f);
        g20 = fmaxf(g20 + b2v.x, 0.f); g21 = fmaxf(g21 + b2v.y, 0.f);
        g30 = fmaxf(g30 + b2v.x, 0.f); g31 = fmaxf(g31 + b2v.y, 0.f);
        float4 q0 = {g00, g10, g20, g30};
        float4 q1 = {g01, g11, g21, g31};
        *(float4*)&h2T[(2 * lane    ) * 16 + col] = q0;
        *(float4*)&h2T[(2 * lane + 1) * 16 + col] = q1;
        __syncthreads();

        float l0=0,l1=0,l2=0,l3=0;
        #pragma unroll
        for (int k = 0; k < H_; k++) {
            float4 h4 = *(const float4*)&h2T[k * 16 + col];
            float w   = W3[k * 64 + lane];
            l0 = fmaf(h4.x, w, l0); l1 = fmaf(h4.y, w, l1);
            l2 = fmaf(h4.z, w, l2); l3 = fmaf(h4.w, w, l3);
        }
        l0 += b3v; l1 += b3v; l2 += b3v; l3 += b3v;

        float m0 = wmax(l0), m1 = wmax(l1), m2 = wmax(l2), m3 = wmax(l3);
        float e0 = __expf(l0 - m0), e1 = __expf(l1 - m1);
        float e2 = __expf(l2 - m2), e3 = __expf(l3 - m3);
        float s0 = wsum(e0), s1 = wsum(e1), s2 = wsum(e2), s3 = wsum(e3);
        em[(size_t)(r0 + 0) * S_ + lane] = e0 / s0;
        em[(size_t)(r0 + 1) * S_ + lane] = e1 / s1;
        em[(size_t)(r0 + 2) * S_ + lane] = e2 / s2;
        em[(size_t)(r0 + 3) * S_ + lane] = e3 / s3;
    }
}

// ---------------- Kernel C: fwd (alpha -> d_out) & bwd (beta -> ws) concurrently.
// Prob-space scaled recursion; mat-vec via readlane broadcast; delayed normalization.
__global__ __launch_bounds__(64) void scan_k(const float* __restrict__ em,
                                             const float* __restrict__ Pm,
                                             const float* __restrict__ PTm,
                                             const float* __restrict__ initp,
                                             float* __restrict__ alpha,   // d_out SP region
                                             float* __restrict__ beta,    // ws
                                             float* __restrict__ ll) {
    int blk = blockIdx.x, lane = threadIdx.x;
    bool isf = blk < B_;
    int b = isf ? blk : blk - B_;
    const float* M = isf ? PTm : Pm;
    float pt[64];
    #pragma unroll
    for (int i = 0; i < 16; i++) {
        float4 v = ((const float4*)(M + lane * 64))[i];
        pt[4*i] = v.x; pt[4*i+1] = v.y; pt[4*i+2] = v.z; pt[4*i+3] = v.w;
    }
    const float* emb = em + (size_t)b * T_ * S_;

    if (isf) {
        float* ap = alpha + (size_t)b * T_ * S_;
        float u = initp[lane] * emb[lane];     // t=0 uses RAW emission (no eps), per reference
        ap[lane] = u;
        float S = wsum(u);
        float rcpS = __builtin_amdgcn_rcpf(S);
        float C = __logf(S);
        float e0, e1, e2, e3;
        e1 = emb[1 * 64 + lane]; e2 = emb[2 * 64 + lane];
        e3 = emb[3 * 64 + lane]; e0 = emb[4 * 64 + lane];

        auto step = [&](int tc, float& es) {
            float ev = es + 1e-10f;
            int rl = tc + 4; if (rl > T_ - 1) rl = T_ - 1;
            es = emb[(size_t)rl * 64 + lane];           // prefetch, consumed 4 steps later
            float a0 = 0, a1 = 0, a2 = 0, a3 = 0;
            #pragma unroll
            for (int k = 0; k < 64; k += 4) {
                a0 = fmaf(rlane(u, k    ), pt[k    ], a0);
                a1 = fmaf(rlane(u, k + 1), pt[k + 1], a1);
                a2 = fmaf(rlane(u, k + 2), pt[k + 2], a2);
                a3 = fmaf(rlane(u, k + 3), pt[k + 3], a3);
            }
            float un = ((a0 + a1) + (a2 + a3)) * ev * rcpS;
            u = un;
            ap[(size_t)tc * 64 + lane] = un;
            float S2 = wsum(un);                         // off critical path (consumed next step)
            rcpS = __builtin_amdgcn_rcpf(S2);
            C += __logf(S2);
        };
        for (int t = 1; t <= T_ - 4; t += 4) {
            step(t, e1); step(t + 1, e2); step(t + 2, e3); step(t + 3, e0);
        }
        step(T_ - 3, e1); step(T_ - 2, e2); step(T_ - 1, e3);
        if (lane == 0) ll[b] = C;                        // ll = sum_t log S_t
    } else {
        float* bp = beta + (size_t)b * T_ * S_;
        float u = 1.f;                                   // beta_{T-1}
        bp[(size_t)(T_ - 1) * 64 + lane] = 1.f;
        float rcpS = 1.f / 64.f;                         // sum of ones
        float e0, e1, e2, e3;
        e3 = emb[(size_t)(T_ - 1) * 64 + lane];
        e2 = emb[(size_t)(T_ - 2) * 64 + lane];
        e1 = emb[(size_t)(T_ - 3) * 64 + lane];
        e0 = emb[(size_t)(T_ - 4) * 64 + lane];

        auto step = [&](int tc, float& es) {
            float ev = es + 1e-10f;                      // em_eps[t+1]
            int rl = tc - 3; if (rl < 0) rl = 0;
            es = emb[(size_t)rl * 64 + lane];
            float v = u * ev;                            // em*beta
            float a0 = 0, a1 = 0, a2 = 0, a3 = 0;
            #pragma unroll
            for (int k = 0; k < 64; k += 4) {
                a0 = fmaf(rlane(v, k    ), pt[k    ], a0);
                a1 = fmaf(rlane(v, k + 1), pt[k + 1], a1);
                a2 = fmaf(rlane(v, k + 2), pt[k + 2], a2);
                a3 = fmaf(rlane(v, k + 3), pt[k + 3], a3);
            }
            float un = ((a0 + a1) + (a2 + a3)) * rcpS;
            u = un;
            bp[(size_t)tc * 64 + lane] = un;
            float S2 = wsum(un);
            rcpS = __builtin_amdgcn_rcpf(S2);
        };
        for (int t = T_ - 2; t >= 3; t -= 4) {
            step(t, e3); step(t - 1, e2); step(t - 2, e1); step(t - 3, e0);
        }
        step(2, e3); step(1, e2); step(0, e1);
    }
}

// ---------------- Kernel D: gamma (in-place over alpha in d_out) + marginals
__global__ __launch_bounds__(256) void gamma_k(const float* __restrict__ beta,
                                               float* __restrict__ out) {
    int wid = threadIdx.x >> 6, lane = threadIdx.x & 63;
    int b = blockIdx.x >> 4;
    int tile = blockIdx.x & 15;
    int t0 = tile * 256 + wid * 64;
    float macc = 0.f;
    size_t base = ((size_t)b * T_ + t0) * 64 + lane;
    for (int i = 0; i < 64; i++) {
        float a  = out[base + (size_t)i * 64];
        float be = beta[((size_t)b * T_ + t0 + i) * 64 + lane];
        float p = a * be;
        float s = wsum(p);
        float g = p * __builtin_amdgcn_rcpf(fmaxf(s, 1e-37f));
        out[base + (size_t)i * 64] = g;
        macc += g;
    }
    atomicAdd(&out[MARG_OFF + b * 64 + lane], macc * (1.0f / T_));
}

extern "C" void kernel_launch(void* const* d_in, const int* in_sizes, int n_in,
                              void* d_out, int out_size, void* d_ws, size_t ws_size,
                              hipStream_t stream) {
    (void)in_sizes; (void)n_in; (void)out_size; (void)ws_size;
    const float* obs    = (const float*)d_in[0];
    const float* W1     = (const float*)d_in[1];
    const float* b1     = (const float*)d_in[2];
    const float* W2     = (const float*)d_in[3];
    const float* b2     = (const float*)d_in[4];
    const float* W3     = (const float*)d_in[5];
    const float* b3     = (const float*)d_in[6];
    const float* LT     = (const float*)d_in[7];
    const float* lip    = (const float*)d_in[8];
    const float* logr   = (const float*)d_in[9];
    const float* logitp = (const float*)d_in[10];
    float* out = (float*)d_out;
    float* ws  = (float*)d_ws;

    hipLaunchKernelGGL(prep_k, dim3(1), dim3(256), 0, stream, LT, lip, logr, logitp, ws, out);
    hipLaunchKernelGGL(mlp_k, dim3(512), dim3(256), 0, stream,
                       obs, W1, b1, W2, b2, W3, b3, ws + EM_OFF);
    hipLaunchKernelGGL(scan_k, dim3(64), dim3(64), 0, stream,
                       ws + EM_OFF, ws + P_OFF, ws + PT_OFF, ws + INITP_OFF,
                       out + SP_OFF, ws + BETA_OFF, out + LL_OFF);
    hipLaunchKernelGGL(gamma_k, dim3(512), dim3(256), 0, stream, ws + BETA_OFF, out);
}

// Round 2
// 1769.224 us; speedup vs baseline: 1.3071x; 1.3071x over previous
//
#include <hip/hip_runtime.h>

#define B_ 32
#define T_ 4096
#define D_ 64
#define H_ 128
#define S_ 64
#define BTS (B_*T_*S_)   /* 8388608 */

// workspace float offsets
#define EM_OFF    0
#define BETA_OFF  BTS
#define P_OFF     (2*BTS)
#define PT_OFF    (2*BTS + 4096)
#define INITP_OFF (2*BTS + 8192)
// output float offsets
#define SP_OFF   0
#define MARG_OFF BTS
#define DUR_OFF  (BTS + 2048)
#define LL_OFF   (BTS + 2112)

__device__ __forceinline__ float wsum(float v) {
    #pragma unroll
    for (int m = 1; m < 64; m <<= 1) v += __shfl_xor(v, m, 64);
    return v;
}
__device__ __forceinline__ float wmax(float v) {
    #pragma unroll
    for (int m = 1; m < 64; m <<= 1) v = fmaxf(v, __shfl_xor(v, m, 64));
    return v;
}
__device__ __forceinline__ float rlane(float v, int k) {
    return __int_as_float(__builtin_amdgcn_readlane(__float_as_int(v), k));
}
// DPP wave64 sum: VALU-only (no lgkmcnt), result complete in lane 63.
template<int CTRL, int RM>
__device__ __forceinline__ float dppadd(float v) {
    return v + __int_as_float(__builtin_amdgcn_update_dpp(
        0, __float_as_int(v), CTRL, RM, 0xf, false));
}
__device__ __forceinline__ float wsum_dpp63(float v) {
    v = dppadd<0x111, 0xf>(v);   // row_shr:1
    v = dppadd<0x112, 0xf>(v);   // row_shr:2
    v = dppadd<0x114, 0xf>(v);   // row_shr:4
    v = dppadd<0x118, 0xf>(v);   // row_shr:8  -> lane15/31/47/63 = row sums
    v = dppadd<0x142, 0xa>(v);   // row_bcast15 -> lane31=r0+r1, lane63=r2+r3
    v = dppadd<0x143, 0xc>(v);   // row_bcast31 -> lane63 = total
    return v;
}

// ---------------- Kernel A: prep (trans probs, init probs, durations, zero marginals)
__global__ __launch_bounds__(256) void prep_k(const float* __restrict__ LT,
                                              const float* __restrict__ lip,
                                              const float* __restrict__ logr,
                                              const float* __restrict__ logitp,
                                              float* __restrict__ ws,
                                              float* __restrict__ out) {
    int tid = threadIdx.x, wid = tid >> 6, lane = tid & 63;
    for (int r = wid; r < S_; r += 4) {
        float x = (lane == r) ? -1e10f : LT[r * S_ + lane];
        float m = wmax(x);
        float e = __expf(x - m);
        float s = wsum(e);
        float p = e / s + 1e-10f;
        ws[P_OFF  + r * S_ + lane] = p;
        ws[PT_OFF + lane * S_ + r] = p;
    }
    if (wid == 0) {
        float x = lip[lane];
        float m = wmax(x);
        float e = __expf(x - m);
        float s = wsum(e);
        ws[INITP_OFF + lane] = e / s;
    } else if (wid == 1) {
        float r = __expf(logr[lane]);
        float p = 1.f / (1.f + __expf(-logitp[lane]));
        out[DUR_OFF + lane] = r * (1.f - p) / p;
    }
    for (int i = tid; i < B_ * S_; i += 256) out[MARG_OFF + i] = 0.f;
}

// ---------------- Kernel B: emission MLP + softmax -> em (B,T,S) fp32
__global__ __launch_bounds__(256) void mlp_k(const float* __restrict__ obs,
                                             const float* __restrict__ W1, const float* __restrict__ b1,
                                             const float* __restrict__ W2, const float* __restrict__ b2,
                                             const float* __restrict__ W3, const float* __restrict__ b3,
                                             float* __restrict__ em) {
    __shared__ float sc[5120];          // xT[64][16] | h1T[128][16] | h2T[128][16]
    float* xT  = sc;
    float* h1T = sc + 1024;
    float* h2T = sc + 3072;
    int tid = threadIdx.x, wid = tid >> 6, lane = tid & 63;
    const float2* W1v = (const float2*)W1;
    const float2* W2v = (const float2*)W2;
    float2 b1v = ((const float2*)b1)[lane];
    float2 b2v = ((const float2*)b2)[lane];
    float  b3v = b3[lane];
    const int col = wid * 4;

    for (int c = blockIdx.x; c < (B_ * T_) / 16; c += gridDim.x) {
        int r0 = c * 16 + wid * 4;
        float4 xv;
        xv.x = obs[(size_t)(r0 + 0) * D_ + lane];
        xv.y = obs[(size_t)(r0 + 1) * D_ + lane];
        xv.z = obs[(size_t)(r0 + 2) * D_ + lane];
        xv.w = obs[(size_t)(r0 + 3) * D_ + lane];
        __syncthreads();                       // prev-chunk LDS reads done
        *(float4*)&xT[lane * 16 + col] = xv;
        __syncthreads();

        float h00=0,h01=0,h10=0,h11=0,h20=0,h21=0,h30=0,h31=0;
        #pragma unroll
        for (int d = 0; d < D_; d++) {
            float4 x4 = *(const float4*)&xT[d * 16 + col];
            float2 w  = W1v[d * 64 + lane];
            h00 = fmaf(x4.x, w.x, h00); h01 = fmaf(x4.x, w.y, h01);
            h10 = fmaf(x4.y, w.x, h10); h11 = fmaf(x4.y, w.y, h11);
            h20 = fmaf(x4.z, w.x, h20); h21 = fmaf(x4.z, w.y, h21);
            h30 = fmaf(x4.w, w.x, h30); h31 = fmaf(x4.w, w.y, h31);
        }
        h00 = fmaxf(h00 + b1v.x, 0.f); h01 = fmaxf(h01 + b1v.y, 0.f);
        h10 = fmaxf(h10 + b1v.x, 0.f); h11 = fmaxf(h11 + b1v.y, 0.f);
        h20 = fmaxf(h20 + b1v.x, 0.f); h21 = fmaxf(h21 + b1v.y, 0.f);
        h30 = fmaxf(h30 + b1v.x, 0.f); h31 = fmaxf(h31 + b1v.y, 0.f);
        float4 p0 = {h00, h10, h20, h30};
        float4 p1 = {h01, h11, h21, h31};
        *(float4*)&h1T[(2 * lane    ) * 16 + col] = p0;
        *(float4*)&h1T[(2 * lane + 1) * 16 + col] = p1;
        __syncthreads();

        float g00=0,g01=0,g10=0,g11=0,g20=0,g21=0,g30=0,g31=0;
        #pragma unroll
        for (int k = 0; k < H_; k++) {
            float4 h4 = *(const float4*)&h1T[k * 16 + col];
            float2 w  = W2v[k * 64 + lane];
            g00 = fmaf(h4.x, w.x, g00); g01 = fmaf(h4.x, w.y, g01);
            g10 = fmaf(h4.y, w.x, g10); g11 = fmaf(h4.y, w.y, g11);
            g20 = fmaf(h4.z, w.x, g20); g21 = fmaf(h4.z, w.y, g21);
            g30 = fmaf(h4.w, w.x, g30); g31 = fmaf(h4.w, w.y, g31);
        }
        g00 = fmaxf(g00 + b2v.x, 0.f); g01 = fmaxf(g01 + b2v.y, 0.f);
        g10 = fmaxf(g10 + b2v.x, 0.f); g11 = fmaxf(g11 + b2v.y, 0.f);
        g20 = fmaxf(g20 + b2v.x, 0.f); g21 = fmaxf(g21 + b2v.y, 0.f);
        g30 = fmaxf(g30 + b2v.x, 0.f); g31 = fmaxf(g31 + b2v.y, 0.f);
        float4 q0 = {g00, g10, g20, g30};
        float4 q1 = {g01, g11, g21, g31};
        *(float4*)&h2T[(2 * lane    ) * 16 + col] = q0;
        *(float4*)&h2T[(2 * lane + 1) * 16 + col] = q1;
        __syncthreads();

        float l0=0,l1=0,l2=0,l3=0;
        #pragma unroll
        for (int k = 0; k < H_; k++) {
            float4 h4 = *(const float4*)&h2T[k * 16 + col];
            float w   = W3[k * 64 + lane];
            l0 = fmaf(h4.x, w, l0); l1 = fmaf(h4.y, w, l1);
            l2 = fmaf(h4.z, w, l2); l3 = fmaf(h4.w, w, l3);
        }
        l0 += b3v; l1 += b3v; l2 += b3v; l3 += b3v;

        float m0 = wmax(l0), m1 = wmax(l1), m2 = wmax(l2), m3 = wmax(l3);
        float e0 = __expf(l0 - m0), e1 = __expf(l1 - m1);
        float e2 = __expf(l2 - m2), e3 = __expf(l3 - m3);
        float s0 = wsum(e0), s1 = wsum(e1), s2 = wsum(e2), s3 = wsum(e3);
        em[(size_t)(r0 + 0) * S_ + lane] = e0 / s0;
        em[(size_t)(r0 + 1) * S_ + lane] = e1 / s1;
        em[(size_t)(r0 + 2) * S_ + lane] = e2 / s2;
        em[(size_t)(r0 + 3) * S_ + lane] = e3 / s3;
    }
}

// ---------------- Kernel C: fwd/bwd recursions, 4 waves per chain.
// Each wave computes a 16-wide partial mat-vec (readlane broadcast), partials
// combined through double-buffered LDS; DPP-based wsum keeps lgkmcnt off the
// pre-barrier drain; normalization one step delayed.
__global__ __launch_bounds__(256) void scan_k(const float* __restrict__ em,
                                              const float* __restrict__ Pm,
                                              const float* __restrict__ PTm,
                                              const float* __restrict__ initp,
                                              float* __restrict__ alpha,   // d_out SP region
                                              float* __restrict__ beta,    // ws
                                              float* __restrict__ ll) {
    __shared__ float part[2][4][64];
    int blk = blockIdx.x, tid = threadIdx.x;
    int lane = tid & 63;
    int w = tid >> 6;
    int kbase = __builtin_amdgcn_readfirstlane(w << 4);
    bool isf = blk < B_;
    int b = isf ? blk : blk - B_;
    const float* M = isf ? PTm : Pm;
    // lane j, this wave's 16-k slice of column j: pt[k'] = M[j*64 + kbase + k']
    float pt[16];
    #pragma unroll
    for (int i = 0; i < 4; i++) {
        float4 v = ((const float4*)(M + lane * 64 + kbase))[i];
        pt[4*i] = v.x; pt[4*i+1] = v.y; pt[4*i+2] = v.z; pt[4*i+3] = v.w;
    }
    const float* emb = em + (size_t)b * T_ * S_;

    if (isf) {
        float* ap = alpha + (size_t)b * T_ * S_;
        float u = initp[lane] * emb[lane];     // t=0 raw emission (no eps), per reference
        if (w == 0) ap[lane] = u;
        float S0 = rlane(wsum_dpp63(u), 63);
        float rcpS = __builtin_amdgcn_rcpf(S0);
        float C = __log2f(S0);
        float e0, e1, e2, e3;
        e1 = emb[1 * 64 + lane]; e2 = emb[2 * 64 + lane];
        e3 = emb[3 * 64 + lane]; e0 = emb[4 * 64 + lane];

        auto step = [&](int tc, float& es) {
            float ev = es + 1e-10f;
            int rl = tc + 4; if (rl > T_ - 1) rl = T_ - 1;
            es = emb[(size_t)rl * 64 + lane];           // consumed 4 steps later
            float p0 = 0, p1 = 0, p2 = 0, p3 = 0;
            #pragma unroll
            for (int k = 0; k < 16; k += 4) {
                p0 = fmaf(rlane(u, kbase + k    ), pt[k    ], p0);
                p1 = fmaf(rlane(u, kbase + k + 1), pt[k + 1], p1);
                p2 = fmaf(rlane(u, kbase + k + 2), pt[k + 2], p2);
                p3 = fmaf(rlane(u, kbase + k + 3), pt[k + 3], p3);
            }
            int buf = tc & 1;
            part[buf][w][lane] = (p0 + p1) + (p2 + p3);
            __syncthreads();
            float tot = (part[buf][0][lane] + part[buf][1][lane]) +
                        (part[buf][2][lane] + part[buf][3][lane]);
            float un = tot * ev * rcpS;
            u = un;
            if (w == (tc & 3)) ap[(size_t)tc * 64 + lane] = un;
            float S = rlane(wsum_dpp63(un), 63);        // consumed next step
            rcpS = __builtin_amdgcn_rcpf(S);
            if (w == 0) C += __log2f(S);
        };
        for (int t = 1; t <= T_ - 4; t += 4) {
            step(t, e1); step(t + 1, e2); step(t + 2, e3); step(t + 3, e0);
        }
        step(T_ - 3, e1); step(T_ - 2, e2); step(T_ - 1, e3);
        if (w == 0 && lane == 0) ll[b] = C * 0.69314718056f;
    } else {
        float* bp = beta + (size_t)b * T_ * S_;
        float u = 1.f;                                   // beta_{T-1}
        if (w == 0) bp[(size_t)(T_ - 1) * 64 + lane] = 1.f;
        float rcpS = 1.f / 64.f;
        float e0, e1, e2, e3;
        e3 = emb[(size_t)(T_ - 1) * 64 + lane];
        e2 = emb[(size_t)(T_ - 2) * 64 + lane];
        e1 = emb[(size_t)(T_ - 3) * 64 + lane];
        e0 = emb[(size_t)(T_ - 4) * 64 + lane];

        auto step = [&](int tc, float& es) {
            float ev = es + 1e-10f;                      // em_eps[t+1]
            int rl = tc - 3; if (rl < 0) rl = 0;
            es = emb[(size_t)rl * 64 + lane];
            float v = u * ev;                            // em*beta
            float p0 = 0, p1 = 0, p2 = 0, p3 = 0;
            #pragma unroll
            for (int k = 0; k < 16; k += 4) {
                p0 = fmaf(rlane(v, kbase + k    ), pt[k    ], p0);
                p1 = fmaf(rlane(v, kbase + k + 1), pt[k + 1], p1);
                p2 = fmaf(rlane(v, kbase + k + 2), pt[k + 2], p2);
                p3 = fmaf(rlane(v, kbase + k + 3), pt[k + 3], p3);
            }
            int buf = tc & 1;
            part[buf][w][lane] = (p0 + p1) + (p2 + p3);
            __syncthreads();
            float tot = (part[buf][0][lane] + part[buf][1][lane]) +
                        (part[buf][2][lane] + part[buf][3][lane]);
            float un = tot * rcpS;
            u = un;
            if (w == (tc & 3)) bp[(size_t)tc * 64 + lane] = un;
            float S = rlane(wsum_dpp63(un), 63);
            rcpS = __builtin_amdgcn_rcpf(S);
        };
        for (int t = T_ - 2; t >= 3; t -= 4) {
            step(t, e3); step(t - 1, e2); step(t - 2, e1); step(t - 3, e0);
        }
        step(2, e3); step(1, e2); step(0, e1);
    }
}

// ---------------- Kernel D: gamma (in-place over alpha in d_out) + marginals
__global__ __launch_bounds__(256) void gamma_k(const float* __restrict__ beta,
                                               float* __restrict__ out) {
    int wid = threadIdx.x >> 6, lane = threadIdx.x & 63;
    int b = blockIdx.x >> 4;
    int tile = blockIdx.x & 15;
    int t0 = tile * 256 + wid * 64;
    float macc = 0.f;
    size_t base = ((size_t)b * T_ + t0) * 64 + lane;
    for (int i = 0; i < 64; i++) {
        float a  = out[base + (size_t)i * 64];
        float be = beta[((size_t)b * T_ + t0 + i) * 64 + lane];
        float p = a * be;
        float s = rlane(wsum_dpp63(p), 63);
        float g = p * __builtin_amdgcn_rcpf(fmaxf(s, 1e-37f));
        out[base + (size_t)i * 64] = g;
        macc += g;
    }
    atomicAdd(&out[MARG_OFF + b * 64 + lane], macc * (1.0f / T_));
}

extern "C" void kernel_launch(void* const* d_in, const int* in_sizes, int n_in,
                              void* d_out, int out_size, void* d_ws, size_t ws_size,
                              hipStream_t stream) {
    (void)in_sizes; (void)n_in; (void)out_size; (void)ws_size;
    const float* obs    = (const float*)d_in[0];
    const float* W1     = (const float*)d_in[1];
    const float* b1     = (const float*)d_in[2];
    const float* W2     = (const float*)d_in[3];
    const float* b2     = (const float*)d_in[4];
    const float* W3     = (const float*)d_in[5];
    const float* b3     = (const float*)d_in[6];
    const float* LT     = (const float*)d_in[7];
    const float* lip    = (const float*)d_in[8];
    const float* logr   = (const float*)d_in[9];
    const float* logitp = (const float*)d_in[10];
    float* out = (float*)d_out;
    float* ws  = (float*)d_ws;

    hipLaunchKernelGGL(prep_k, dim3(1), dim3(256), 0, stream, LT, lip, logr, logitp, ws, out);
    hipLaunchKernelGGL(mlp_k, dim3(512), dim3(256), 0, stream,
                       obs, W1, b1, W2, b2, W3, b3, ws + EM_OFF);
    hipLaunchKernelGGL(scan_k, dim3(64), dim3(256), 0, stream,
                       ws + EM_OFF, ws + P_OFF, ws + PT_OFF, ws + INITP_OFF,
                       out + SP_OFF, ws + BETA_OFF, out + LL_OFF);
    hipLaunchKernelGGL(gamma_k, dim3(512), dim3(256), 0, stream, ws + BETA_OFF, out);
}

// Round 3
// 972.422 us; speedup vs baseline: 2.3782x; 1.8194x over previous
//
#include <hip/hip_runtime.h>

#define B_ 32
#define T_ 4096
#define D_ 64
#define H_ 128
#define S_ 64
#define BTS (B_*T_*S_)   /* 8388608 */

#define NCH 16      /* chunks per sequence */
#define CL  256     /* chunk length */

// workspace float offsets
#define EM_OFF    0
#define BETA_OFF  BTS
#define P_OFF     (2*BTS)
#define PT_OFF    (2*BTS + 4096)
#define INITP_OFF (2*BTS + 8192)
// output float offsets
#define SP_OFF   0
#define MARG_OFF BTS
#define DUR_OFF  (BTS + 2048)
#define LL_OFF   (BTS + 2112)

__device__ __forceinline__ float wsum(float v) {
    #pragma unroll
    for (int m = 1; m < 64; m <<= 1) v += __shfl_xor(v, m, 64);
    return v;
}
__device__ __forceinline__ float wmax(float v) {
    #pragma unroll
    for (int m = 1; m < 64; m <<= 1) v = fmaxf(v, __shfl_xor(v, m, 64));
    return v;
}
__device__ __forceinline__ float rlane(float v, int k) {
    return __int_as_float(__builtin_amdgcn_readlane(__float_as_int(v), k));
}
// DPP wave64 sum: VALU-only (no lgkmcnt), result complete in lane 63.
template<int CTRL, int RM>
__device__ __forceinline__ float dppadd(float v) {
    return v + __int_as_float(__builtin_amdgcn_update_dpp(
        0, __float_as_int(v), CTRL, RM, 0xf, false));
}
__device__ __forceinline__ float wsum_dpp63(float v) {
    v = dppadd<0x111, 0xf>(v);   // row_shr:1
    v = dppadd<0x112, 0xf>(v);   // row_shr:2
    v = dppadd<0x114, 0xf>(v);   // row_shr:4
    v = dppadd<0x118, 0xf>(v);   // row_shr:8
    v = dppadd<0x142, 0xa>(v);   // row_bcast15
    v = dppadd<0x143, 0xc>(v);   // row_bcast31 -> lane63 = total
    return v;
}

// ---------------- Kernel A: prep (trans probs, init probs, durations, zero marginals+ll)
__global__ __launch_bounds__(256) void prep_k(const float* __restrict__ LT,
                                              const float* __restrict__ lip,
                                              const float* __restrict__ logr,
                                              const float* __restrict__ logitp,
                                              float* __restrict__ ws,
                                              float* __restrict__ out) {
    int tid = threadIdx.x, wid = tid >> 6, lane = tid & 63;
    for (int r = wid; r < S_; r += 4) {
        float x = (lane == r) ? -1e10f : LT[r * S_ + lane];
        float m = wmax(x);
        float e = __expf(x - m);
        float s = wsum(e);
        float p = e / s + 1e-10f;
        ws[P_OFF  + r * S_ + lane] = p;
        ws[PT_OFF + lane * S_ + r] = p;
    }
    if (wid == 0) {
        float x = lip[lane];
        float m = wmax(x);
        float e = __expf(x - m);
        float s = wsum(e);
        ws[INITP_OFF + lane] = e / s;
    } else if (wid == 1) {
        float r = __expf(logr[lane]);
        float p = 1.f / (1.f + __expf(-logitp[lane]));
        out[DUR_OFF + lane] = r * (1.f - p) / p;
    }
    for (int i = tid; i < B_ * S_; i += 256) out[MARG_OFF + i] = 0.f;
    if (tid < B_) out[LL_OFF + tid] = 0.f;   // ll accumulated via atomicAdd
}

// ---------------- Kernel B: emission MLP + softmax -> em (B,T,S) fp32
__global__ __launch_bounds__(256) void mlp_k(const float* __restrict__ obs,
                                             const float* __restrict__ W1, const float* __restrict__ b1,
                                             const float* __restrict__ W2, const float* __restrict__ b2,
                                             const float* __restrict__ W3, const float* __restrict__ b3,
                                             float* __restrict__ em) {
    __shared__ float sc[5120];          // xT[64][16] | h1T[128][16] | h2T[128][16]
    float* xT  = sc;
    float* h1T = sc + 1024;
    float* h2T = sc + 3072;
    int tid = threadIdx.x, wid = tid >> 6, lane = tid & 63;
    const float2* W1v = (const float2*)W1;
    const float2* W2v = (const float2*)W2;
    float2 b1v = ((const float2*)b1)[lane];
    float2 b2v = ((const float2*)b2)[lane];
    float  b3v = b3[lane];
    const int col = wid * 4;

    for (int c = blockIdx.x; c < (B_ * T_) / 16; c += gridDim.x) {
        int r0 = c * 16 + wid * 4;
        float4 xv;
        xv.x = obs[(size_t)(r0 + 0) * D_ + lane];
        xv.y = obs[(size_t)(r0 + 1) * D_ + lane];
        xv.z = obs[(size_t)(r0 + 2) * D_ + lane];
        xv.w = obs[(size_t)(r0 + 3) * D_ + lane];
        __syncthreads();                       // prev-chunk LDS reads done
        *(float4*)&xT[lane * 16 + col] = xv;
        __syncthreads();

        float h00=0,h01=0,h10=0,h11=0,h20=0,h21=0,h30=0,h31=0;
        #pragma unroll
        for (int d = 0; d < D_; d++) {
            float4 x4 = *(const float4*)&xT[d * 16 + col];
            float2 w  = W1v[d * 64 + lane];
            h00 = fmaf(x4.x, w.x, h00); h01 = fmaf(x4.x, w.y, h01);
            h10 = fmaf(x4.y, w.x, h10); h11 = fmaf(x4.y, w.y, h11);
            h20 = fmaf(x4.z, w.x, h20); h21 = fmaf(x4.z, w.y, h21);
            h30 = fmaf(x4.w, w.x, h30); h31 = fmaf(x4.w, w.y, h31);
        }
        h00 = fmaxf(h00 + b1v.x, 0.f); h01 = fmaxf(h01 + b1v.y, 0.f);
        h10 = fmaxf(h10 + b1v.x, 0.f); h11 = fmaxf(h11 + b1v.y, 0.f);
        h20 = fmaxf(h20 + b1v.x, 0.f); h21 = fmaxf(h21 + b1v.y, 0.f);
        h30 = fmaxf(h30 + b1v.x, 0.f); h31 = fmaxf(h31 + b1v.y, 0.f);
        float4 p0 = {h00, h10, h20, h30};
        float4 p1 = {h01, h11, h21, h31};
        *(float4*)&h1T[(2 * lane    ) * 16 + col] = p0;
        *(float4*)&h1T[(2 * lane + 1) * 16 + col] = p1;
        __syncthreads();

        float g00=0,g01=0,g10=0,g11=0,g20=0,g21=0,g30=0,g31=0;
        #pragma unroll
        for (int k = 0; k < H_; k++) {
            float4 h4 = *(const float4*)&h1T[k * 16 + col];
            float2 w  = W2v[k * 64 + lane];
            g00 = fmaf(h4.x, w.x, g00); g01 = fmaf(h4.x, w.y, g01);
            g10 = fmaf(h4.y, w.x, g10); g11 = fmaf(h4.y, w.y, g11);
            g20 = fmaf(h4.z, w.x, g20); g21 = fmaf(h4.z, w.y, g21);
            g30 = fmaf(h4.w, w.x, g30); g31 = fmaf(h4.w, w.y, g31);
        }
        g00 = fmaxf(g00 + b2v.x, 0.f); g01 = fmaxf(g01 + b2v.y, 0.f);
        g10 = fmaxf(g10 + b2v.x, 0.f); g11 = fmaxf(g11 + b2v.y, 0.f);
        g20 = fmaxf(g20 + b2v.x, 0.f); g21 = fmaxf(g21 + b2v.y, 0.f);
        g30 = fmaxf(g30 + b2v.x, 0.f); g31 = fmaxf(g31 + b2v.y, 0.f);
        float4 q0 = {g00, g10, g20, g30};
        float4 q1 = {g01, g11, g21, g31};
        *(float4*)&h2T[(2 * lane    ) * 16 + col] = q0;
        *(float4*)&h2T[(2 * lane + 1) * 16 + col] = q1;
        __syncthreads();

        float l0=0,l1=0,l2=0,l3=0;
        #pragma unroll
        for (int k = 0; k < H_; k++) {
            float4 h4 = *(const float4*)&h2T[k * 16 + col];
            float w   = W3[k * 64 + lane];
            l0 = fmaf(h4.x, w, l0); l1 = fmaf(h4.y, w, l1);
            l2 = fmaf(h4.z, w, l2); l3 = fmaf(h4.w, w, l3);
        }
        l0 += b3v; l1 += b3v; l2 += b3v; l3 += b3v;

        float m0 = wmax(l0), m1 = wmax(l1), m2 = wmax(l2), m3 = wmax(l3);
        float e0 = __expf(l0 - m0), e1 = __expf(l1 - m1);
        float e2 = __expf(l2 - m2), e3 = __expf(l3 - m3);
        float s0 = wsum(e0), s1 = wsum(e1), s2 = wsum(e2), s3 = wsum(e3);
        em[(size_t)(r0 + 0) * S_ + lane] = e0 / s0;
        em[(size_t)(r0 + 1) * S_ + lane] = e1 / s1;
        em[(size_t)(r0 + 2) * S_ + lane] = e2 / s2;
        em[(size_t)(r0 + 3) * S_ + lane] = e3 / s3;
    }
}

// ---------------- Kernel C: chunked fwd/bwd recursions, 4 waves per chain.
// T split into NCH chunks of CL; each chunk warms up ~32 discarded steps from a
// proxy start (projective contraction of diag(e)·M forgets the start vector),
// then computes its CL steps exactly. Per-chunk sum(log S_t) atomicAdd'd to ll.
__global__ __launch_bounds__(256) void scan_k(const float* __restrict__ em,
                                              const float* __restrict__ Pm,
                                              const float* __restrict__ PTm,
                                              const float* __restrict__ initp,
                                              float* __restrict__ alpha,   // d_out SP region
                                              float* __restrict__ beta,    // ws
                                              float* __restrict__ ll) {
    __shared__ float part[2][4][64];
    int blk = blockIdx.x, tid = threadIdx.x;
    int lane = tid & 63;
    int w = tid >> 6;
    int kbase = __builtin_amdgcn_readfirstlane(w << 4);
    bool isf = blk < B_ * NCH;
    int lin  = isf ? blk : blk - B_ * NCH;
    int b = lin >> 4;
    int ch = lin & (NCH - 1);
    const float* M = isf ? PTm : Pm;
    float pt[16];
    #pragma unroll
    for (int i = 0; i < 4; i++) {
        float4 v = ((const float4*)(M + lane * 64 + kbase))[i];
        pt[4*i] = v.x; pt[4*i+1] = v.y; pt[4*i+2] = v.z; pt[4*i+3] = v.w;
    }
    const float* emb = em + (size_t)b * T_ * S_;

    if (isf) {
        float* ap = alpha + (size_t)b * T_ * S_;
        const int wlo = ch * CL;                 // first owned timestep
        const int te  = wlo + CL - 1;            // last owned timestep
        float u, rcpS, C;
        int ts;
        if (ch == 0) {
            u = initp[lane] * emb[lane];         // t=0 raw emission (no eps), per reference
            if (w == 0) ap[lane] = u;
            float S0 = rlane(wsum_dpp63(u), 63);
            rcpS = __builtin_amdgcn_rcpf(S0);
            C = __log2f(S0);
            ts = 1;
        } else {
            ts = wlo - 32;                       // 32 warm-up steps
            u = emb[(size_t)(ts - 1) * S_ + lane] + 1e-10f;   // proxy start direction
            float S0 = rlane(wsum_dpp63(u), 63);
            rcpS = __builtin_amdgcn_rcpf(S0);
            C = 0.f;
        }
        float ec = emb[(size_t)ts * S_ + lane];
        float e1 = emb[(size_t)(ts + 1) * S_ + lane];
        float e2 = emb[(size_t)(ts + 2) * S_ + lane];
        for (int t = ts; t <= te; t++) {
            float ev = ec + 1e-10f;
            ec = e1; e1 = e2;
            int tn = t + 3 > te ? te : t + 3;
            e2 = emb[(size_t)tn * S_ + lane];    // consumed 3 steps later
            float p0 = 0, p1 = 0, p2 = 0, p3 = 0;
            #pragma unroll
            for (int k = 0; k < 16; k += 4) {
                p0 = fmaf(rlane(u, kbase + k    ), pt[k    ], p0);
                p1 = fmaf(rlane(u, kbase + k + 1), pt[k + 1], p1);
                p2 = fmaf(rlane(u, kbase + k + 2), pt[k + 2], p2);
                p3 = fmaf(rlane(u, kbase + k + 3), pt[k + 3], p3);
            }
            int buf = t & 1;
            part[buf][w][lane] = (p0 + p1) + (p2 + p3);
            __syncthreads();
            float tot = (part[buf][0][lane] + part[buf][1][lane]) +
                        (part[buf][2][lane] + part[buf][3][lane]);
            float un = tot * ev * rcpS;
            u = un;
            if (t >= wlo && w == (t & 3)) ap[(size_t)t * S_ + lane] = un;
            float S = rlane(wsum_dpp63(un), 63); // consumed next step
            rcpS = __builtin_amdgcn_rcpf(S);
            if (w == 0 && t >= wlo) C += __log2f(S);
        }
        if (w == 0 && lane == 0) atomicAdd(&ll[b], C * 0.69314718056f);
    } else {
        float* bp = beta + (size_t)b * T_ * S_;
        const int whi = (ch + 1) * CL - 1;       // last owned timestep
        const int tlo = ch * CL;                 // first owned timestep
        float u, rcpS;
        int ts;
        if (ch == NCH - 1) {
            u = 1.f;                             // beta_{T-1}
            if (w == 0) bp[(size_t)(T_ - 1) * S_ + lane] = 1.f;
            rcpS = 1.f / 64.f;
            ts = T_ - 2;
        } else {
            ts = whi + 31;                       // 31 warm-up steps (computes down to whi+1)
            u = 1.f;                             // proxy beta at ts+1
            rcpS = 1.f / 64.f;
        }
        float ec = emb[(size_t)(ts + 1) * S_ + lane];
        float e1 = emb[(size_t)ts * S_ + lane];
        float e2 = emb[(size_t)(ts - 1) * S_ + lane];
        for (int t = ts; t >= tlo; t--) {
            float ev = ec + 1e-10f;              // em_eps[t+1]
            ec = e1; e1 = e2;
            int tp = t - 2 < 0 ? 0 : t - 2;      // = (t-3)+1
            e2 = emb[(size_t)tp * S_ + lane];
            float v = u * ev;                    // em*beta
            float p0 = 0, p1 = 0, p2 = 0, p3 = 0;
            #pragma unroll
            for (int k = 0; k < 16; k += 4) {
                p0 = fmaf(rlane(v, kbase + k    ), pt[k    ], p0);
                p1 = fmaf(rlane(v, kbase + k + 1), pt[k + 1], p1);
                p2 = fmaf(rlane(v, kbase + k + 2), pt[k + 2], p2);
                p3 = fmaf(rlane(v, kbase + k + 3), pt[k + 3], p3);
            }
            int buf = t & 1;
            part[buf][w][lane] = (p0 + p1) + (p2 + p3);
            __syncthreads();
            float tot = (part[buf][0][lane] + part[buf][1][lane]) +
                        (part[buf][2][lane] + part[buf][3][lane]);
            float un = tot * rcpS;
            u = un;
            if (t <= whi && w == (t & 3)) bp[(size_t)t * S_ + lane] = un;
            float S = rlane(wsum_dpp63(un), 63);
            rcpS = __builtin_amdgcn_rcpf(S);
        }
    }
}

// ---------------- Kernel D: gamma (in-place over alpha in d_out) + marginals
__global__ __launch_bounds__(256) void gamma_k(const float* __restrict__ beta,
                                               float* __restrict__ out) {
    int wid = threadIdx.x >> 6, lane = threadIdx.x & 63;
    int b = blockIdx.x >> 4;
    int tile = blockIdx.x & 15;
    int t0 = tile * 256 + wid * 64;
    float macc = 0.f;
    size_t base = ((size_t)b * T_ + t0) * 64 + lane;
    for (int i = 0; i < 64; i++) {
        float a  = out[base + (size_t)i * 64];
        float be = beta[((size_t)b * T_ + t0 + i) * 64 + lane];
        float p = a * be;
        float s = rlane(wsum_dpp63(p), 63);
        float g = p * __builtin_amdgcn_rcpf(fmaxf(s, 1e-37f));
        out[base + (size_t)i * 64] = g;
        macc += g;
    }
    atomicAdd(&out[MARG_OFF + b * 64 + lane], macc * (1.0f / T_));
}

extern "C" void kernel_launch(void* const* d_in, const int* in_sizes, int n_in,
                              void* d_out, int out_size, void* d_ws, size_t ws_size,
                              hipStream_t stream) {
    (void)in_sizes; (void)n_in; (void)out_size; (void)ws_size;
    const float* obs    = (const float*)d_in[0];
    const float* W1     = (const float*)d_in[1];
    const float* b1     = (const float*)d_in[2];
    const float* W2     = (const float*)d_in[3];
    const float* b2     = (const float*)d_in[4];
    const float* W3     = (const float*)d_in[5];
    const float* b3     = (const float*)d_in[6];
    const float* LT     = (const float*)d_in[7];
    const float* lip    = (const float*)d_in[8];
    const float* logr   = (const float*)d_in[9];
    const float* logitp = (const float*)d_in[10];
    float* out = (float*)d_out;
    float* ws  = (float*)d_ws;

    hipLaunchKernelGGL(prep_k, dim3(1), dim3(256), 0, stream, LT, lip, logr, logitp, ws, out);
    hipLaunchKernelGGL(mlp_k, dim3(512), dim3(256), 0, stream,
                       obs, W1, b1, W2, b2, W3, b3, ws + EM_OFF);
    hipLaunchKernelGGL(scan_k, dim3(2 * B_ * NCH), dim3(256), 0, stream,
                       ws + EM_OFF, ws + P_OFF, ws + PT_OFF, ws + INITP_OFF,
                       out + SP_OFF, ws + BETA_OFF, out + LL_OFF);
    hipLaunchKernelGGL(gamma_k, dim3(512), dim3(256), 0, stream, ws + BETA_OFF, out);
}

// Round 4
// 460.768 us; speedup vs baseline: 5.0190x; 2.1104x over previous
//
#include <hip/hip_runtime.h>

#define B_ 32
#define T_ 4096
#define D_ 64
#define H_ 128
#define S_ 64
#define BTS (B_*T_*S_)   /* 8388608 */

#define NCH 16      /* chunks per sequence */
#define CL  256     /* chunk length */

// workspace float offsets
#define EM_OFF    0
#define BETA_OFF  BTS
#define P_OFF     (2*BTS)
#define PT_OFF    (2*BTS + 4096)
#define INITP_OFF (2*BTS + 8192)
// output float offsets
#define SP_OFF   0
#define MARG_OFF BTS
#define DUR_OFF  (BTS + 2048)
#define LL_OFF   (BTS + 2112)

__device__ __forceinline__ float wsum(float v) {
    #pragma unroll
    for (int m = 1; m < 64; m <<= 1) v += __shfl_xor(v, m, 64);
    return v;
}
__device__ __forceinline__ float wmax(float v) {
    #pragma unroll
    for (int m = 1; m < 64; m <<= 1) v = fmaxf(v, __shfl_xor(v, m, 64));
    return v;
}
__device__ __forceinline__ float rlane(float v, int k) {
    return __int_as_float(__builtin_amdgcn_readlane(__float_as_int(v), k));
}
// DPP wave64 sum: VALU-only (no lgkmcnt), result complete in lane 63.
template<int CTRL, int RM>
__device__ __forceinline__ float dppadd(float v) {
    return v + __int_as_float(__builtin_amdgcn_update_dpp(
        0, __float_as_int(v), CTRL, RM, 0xf, false));
}
__device__ __forceinline__ float wsum_dpp63(float v) {
    v = dppadd<0x111, 0xf>(v);   // row_shr:1
    v = dppadd<0x112, 0xf>(v);   // row_shr:2
    v = dppadd<0x114, 0xf>(v);   // row_shr:4
    v = dppadd<0x118, 0xf>(v);   // row_shr:8
    v = dppadd<0x142, 0xa>(v);   // row_bcast15
    v = dppadd<0x143, 0xc>(v);   // row_bcast31 -> lane63 = total
    return v;
}

// ---------------- Kernel A: prep (trans probs, init probs, durations, zero marginals+ll)
__global__ __launch_bounds__(256) void prep_k(const float* __restrict__ LT,
                                              const float* __restrict__ lip,
                                              const float* __restrict__ logr,
                                              const float* __restrict__ logitp,
                                              float* __restrict__ ws,
                                              float* __restrict__ out) {
    int tid = threadIdx.x, wid = tid >> 6, lane = tid & 63;
    for (int r = wid; r < S_; r += 4) {
        float x = (lane == r) ? -1e10f : LT[r * S_ + lane];
        float m = wmax(x);
        float e = __expf(x - m);
        float s = wsum(e);
        float p = e / s + 1e-10f;
        ws[P_OFF  + r * S_ + lane] = p;
        ws[PT_OFF + lane * S_ + r] = p;
    }
    if (wid == 0) {
        float x = lip[lane];
        float m = wmax(x);
        float e = __expf(x - m);
        float s = wsum(e);
        ws[INITP_OFF + lane] = e / s;
    } else if (wid == 1) {
        float r = __expf(logr[lane]);
        float p = 1.f / (1.f + __expf(-logitp[lane]));
        out[DUR_OFF + lane] = r * (1.f - p) / p;
    }
    for (int i = tid; i < B_ * S_; i += 256) out[MARG_OFF + i] = 0.f;
    if (tid < B_) out[LL_OFF + tid] = 0.f;   // ll accumulated via atomicAdd
}

// ---------------- Kernel B: emission MLP + softmax -> em (B,T,S) fp32
// Fully intra-wave: each wave owns 8 rows end-to-end; no __syncthreads.
// LDS pad-12 layouts: per-lane b128 writes conflict-free, per-k b128 reads
// wave-uniform (bank broadcast). h2 unions with x (disjoint lifetimes).
__global__ __launch_bounds__(256) void mlp_k(const float* __restrict__ obs,
                                             const float* __restrict__ W1, const float* __restrict__ b1,
                                             const float* __restrict__ W2, const float* __restrict__ b2,
                                             const float* __restrict__ W3, const float* __restrict__ b3,
                                             float* __restrict__ em) {
    __shared__ float lds[12288];              // 4 waves * 3072 floats (48 KB)
    int tid = threadIdx.x, wid = tid >> 6, lane = tid & 63;
    const int base  = wid * 3072;
    const int xoff  = base;                   // x[d][12],  d<64   (union w/ h2)
    const int h2off = base;                   // h2[k][12], k<128
    const int h1off = base + 1536;            // h1[k][12], k<128
    const float2* W1v = (const float2*)W1;
    const float2* W2v = (const float2*)W2;
    float2 b1v = ((const float2*)b1)[lane];
    float2 b2v = ((const float2*)b2)[lane];
    float  b3v = b3[lane];

    int gw = blockIdx.x * 4 + wid;            // global wave id
    for (int c = gw; c < (B_ * T_) / 8; c += gridDim.x * 4) {
        int r0 = c * 8;
        // ---- stage 8 rows: lane = dim d, x[d][i] ----
        float v0 = obs[(size_t)(r0 + 0) * D_ + lane];
        float v1 = obs[(size_t)(r0 + 1) * D_ + lane];
        float v2 = obs[(size_t)(r0 + 2) * D_ + lane];
        float v3 = obs[(size_t)(r0 + 3) * D_ + lane];
        float v4 = obs[(size_t)(r0 + 4) * D_ + lane];
        float v5 = obs[(size_t)(r0 + 5) * D_ + lane];
        float v6 = obs[(size_t)(r0 + 6) * D_ + lane];
        float v7 = obs[(size_t)(r0 + 7) * D_ + lane];
        float4 xa = {v0, v1, v2, v3};
        float4 xb = {v4, v5, v6, v7};
        *(float4*)&lds[xoff + lane * 12    ] = xa;
        *(float4*)&lds[xoff + lane * 12 + 4] = xb;
        __asm__ __volatile__("s_waitcnt lgkmcnt(0)" ::: "memory");

        // ---- layer 1: h1[j] = relu(sum_d x[d]*W1[d][j]), j = 2*lane+{0,1} ----
        float hx[8] = {0,0,0,0,0,0,0,0};
        float hy[8] = {0,0,0,0,0,0,0,0};
        #pragma unroll 4
        for (int d = 0; d < D_; d++) {
            float4 a = *(const float4*)&lds[xoff + d * 12];
            float4 b = *(const float4*)&lds[xoff + d * 12 + 4];
            float2 w = W1v[d * 64 + lane];
            hx[0] = fmaf(a.x, w.x, hx[0]); hy[0] = fmaf(a.x, w.y, hy[0]);
            hx[1] = fmaf(a.y, w.x, hx[1]); hy[1] = fmaf(a.y, w.y, hy[1]);
            hx[2] = fmaf(a.z, w.x, hx[2]); hy[2] = fmaf(a.z, w.y, hy[2]);
            hx[3] = fmaf(a.w, w.x, hx[3]); hy[3] = fmaf(a.w, w.y, hy[3]);
            hx[4] = fmaf(b.x, w.x, hx[4]); hy[4] = fmaf(b.x, w.y, hy[4]);
            hx[5] = fmaf(b.y, w.x, hx[5]); hy[5] = fmaf(b.y, w.y, hy[5]);
            hx[6] = fmaf(b.z, w.x, hx[6]); hy[6] = fmaf(b.z, w.y, hy[6]);
            hx[7] = fmaf(b.w, w.x, hx[7]); hy[7] = fmaf(b.w, w.y, hy[7]);
        }
        #pragma unroll
        for (int i = 0; i < 8; i++) {
            hx[i] = fmaxf(hx[i] + b1v.x, 0.f);
            hy[i] = fmaxf(hy[i] + b1v.y, 0.f);
        }
        float4 p0 = {hx[0], hx[1], hx[2], hx[3]};
        float4 p1 = {hx[4], hx[5], hx[6], hx[7]};
        float4 q0 = {hy[0], hy[1], hy[2], hy[3]};
        float4 q1 = {hy[4], hy[5], hy[6], hy[7]};
        *(float4*)&lds[h1off + (2 * lane    ) * 12    ] = p0;
        *(float4*)&lds[h1off + (2 * lane    ) * 12 + 4] = p1;
        *(float4*)&lds[h1off + (2 * lane + 1) * 12    ] = q0;
        *(float4*)&lds[h1off + (2 * lane + 1) * 12 + 4] = q1;
        __asm__ __volatile__("s_waitcnt lgkmcnt(0)" ::: "memory");

        // ---- layer 2: h2[j] = relu(sum_k h1[k]*W2[k][j]) ----
        float gx[8] = {0,0,0,0,0,0,0,0};
        float gy[8] = {0,0,0,0,0,0,0,0};
        #pragma unroll 4
        for (int k = 0; k < H_; k++) {
            float4 a = *(const float4*)&lds[h1off + k * 12];
            float4 b = *(const float4*)&lds[h1off + k * 12 + 4];
            float2 w = W2v[k * 64 + lane];
            gx[0] = fmaf(a.x, w.x, gx[0]); gy[0] = fmaf(a.x, w.y, gy[0]);
            gx[1] = fmaf(a.y, w.x, gx[1]); gy[1] = fmaf(a.y, w.y, gy[1]);
            gx[2] = fmaf(a.z, w.x, gx[2]); gy[2] = fmaf(a.z, w.y, gy[2]);
            gx[3] = fmaf(a.w, w.x, gx[3]); gy[3] = fmaf(a.w, w.y, gy[3]);
            gx[4] = fmaf(b.x, w.x, gx[4]); gy[4] = fmaf(b.x, w.y, gy[4]);
            gx[5] = fmaf(b.y, w.x, gx[5]); gy[5] = fmaf(b.y, w.y, gy[5]);
            gx[6] = fmaf(b.z, w.x, gx[6]); gy[6] = fmaf(b.z, w.y, gy[6]);
            gx[7] = fmaf(b.w, w.x, gx[7]); gy[7] = fmaf(b.w, w.y, gy[7]);
        }
        #pragma unroll
        for (int i = 0; i < 8; i++) {
            gx[i] = fmaxf(gx[i] + b2v.x, 0.f);
            gy[i] = fmaxf(gy[i] + b2v.y, 0.f);
        }
        p0 = {gx[0], gx[1], gx[2], gx[3]};
        p1 = {gx[4], gx[5], gx[6], gx[7]};
        q0 = {gy[0], gy[1], gy[2], gy[3]};
        q1 = {gy[4], gy[5], gy[6], gy[7]};
        *(float4*)&lds[h2off + (2 * lane    ) * 12    ] = p0;
        *(float4*)&lds[h2off + (2 * lane    ) * 12 + 4] = p1;
        *(float4*)&lds[h2off + (2 * lane + 1) * 12    ] = q0;
        *(float4*)&lds[h2off + (2 * lane + 1) * 12 + 4] = q1;
        __asm__ __volatile__("s_waitcnt lgkmcnt(0)" ::: "memory");

        // ---- layer 3: logits[s] = sum_k h2[k]*W3[k][s], s = lane ----
        float l[8] = {0,0,0,0,0,0,0,0};
        #pragma unroll 4
        for (int k = 0; k < H_; k++) {
            float4 a = *(const float4*)&lds[h2off + k * 12];
            float4 b = *(const float4*)&lds[h2off + k * 12 + 4];
            float w  = W3[k * 64 + lane];
            l[0] = fmaf(a.x, w, l[0]); l[1] = fmaf(a.y, w, l[1]);
            l[2] = fmaf(a.z, w, l[2]); l[3] = fmaf(a.w, w, l[3]);
            l[4] = fmaf(b.x, w, l[4]); l[5] = fmaf(b.y, w, l[5]);
            l[6] = fmaf(b.z, w, l[6]); l[7] = fmaf(b.w, w, l[7]);
        }
        // ---- softmax per row across lanes + store ----
        #pragma unroll
        for (int i = 0; i < 8; i++) {
            float li = l[i] + b3v;
            float m = wmax(li);
            float e = __expf(li - m);
            float s = wsum(e);
            em[(size_t)(r0 + i) * S_ + lane] = e * __builtin_amdgcn_rcpf(s);
        }
    }
}

// ---------------- Kernel C: chunked fwd/bwd recursions, 4 waves per chain.
__global__ __launch_bounds__(256) void scan_k(const float* __restrict__ em,
                                              const float* __restrict__ Pm,
                                              const float* __restrict__ PTm,
                                              const float* __restrict__ initp,
                                              float* __restrict__ alpha,   // d_out SP region
                                              float* __restrict__ beta,    // ws
                                              float* __restrict__ ll) {
    __shared__ float part[2][4][64];
    int blk = blockIdx.x, tid = threadIdx.x;
    int lane = tid & 63;
    int w = tid >> 6;
    int kbase = __builtin_amdgcn_readfirstlane(w << 4);
    bool isf = blk < B_ * NCH;
    int lin  = isf ? blk : blk - B_ * NCH;
    int b = lin >> 4;
    int ch = lin & (NCH - 1);
    const float* M = isf ? PTm : Pm;
    float pt[16];
    #pragma unroll
    for (int i = 0; i < 4; i++) {
        float4 v = ((const float4*)(M + lane * 64 + kbase))[i];
        pt[4*i] = v.x; pt[4*i+1] = v.y; pt[4*i+2] = v.z; pt[4*i+3] = v.w;
    }
    const float* emb = em + (size_t)b * T_ * S_;

    if (isf) {
        float* ap = alpha + (size_t)b * T_ * S_;
        const int wlo = ch * CL;                 // first owned timestep
        const int te  = wlo + CL - 1;            // last owned timestep
        float u, rcpS, C;
        int ts;
        if (ch == 0) {
            u = initp[lane] * emb[lane];         // t=0 raw emission (no eps), per reference
            if (w == 0) ap[lane] = u;
            float S0 = rlane(wsum_dpp63(u), 63);
            rcpS = __builtin_amdgcn_rcpf(S0);
            C = __log2f(S0);
            ts = 1;
        } else {
            ts = wlo - 32;                       // 32 warm-up steps
            u = emb[(size_t)(ts - 1) * S_ + lane] + 1e-10f;   // proxy start direction
            float S0 = rlane(wsum_dpp63(u), 63);
            rcpS = __builtin_amdgcn_rcpf(S0);
            C = 0.f;
        }
        float ec = emb[(size_t)ts * S_ + lane];
        float e1 = emb[(size_t)(ts + 1) * S_ + lane];
        float e2 = emb[(size_t)(ts + 2) * S_ + lane];
        for (int t = ts; t <= te; t++) {
            float ev = ec + 1e-10f;
            ec = e1; e1 = e2;
            int tn = t + 3 > te ? te : t + 3;
            e2 = emb[(size_t)tn * S_ + lane];    // consumed 3 steps later
            float p0 = 0, p1 = 0, p2 = 0, p3 = 0;
            #pragma unroll
            for (int k = 0; k < 16; k += 4) {
                p0 = fmaf(rlane(u, kbase + k    ), pt[k    ], p0);
                p1 = fmaf(rlane(u, kbase + k + 1), pt[k + 1], p1);
                p2 = fmaf(rlane(u, kbase + k + 2), pt[k + 2], p2);
                p3 = fmaf(rlane(u, kbase + k + 3), pt[k + 3], p3);
            }
            int buf = t & 1;
            part[buf][w][lane] = (p0 + p1) + (p2 + p3);
            __syncthreads();
            float tot = (part[buf][0][lane] + part[buf][1][lane]) +
                        (part[buf][2][lane] + part[buf][3][lane]);
            float un = tot * ev * rcpS;
            u = un;
            if (t >= wlo && w == (t & 3)) ap[(size_t)t * S_ + lane] = un;
            float S = rlane(wsum_dpp63(un), 63); // consumed next step
            rcpS = __builtin_amdgcn_rcpf(S);
            if (w == 0 && t >= wlo) C += __log2f(S);
        }
        if (w == 0 && lane == 0) atomicAdd(&ll[b], C * 0.69314718056f);
    } else {
        float* bp = beta + (size_t)b * T_ * S_;
        const int whi = (ch + 1) * CL - 1;       // last owned timestep
        const int tlo = ch * CL;                 // first owned timestep
        float u, rcpS;
        int ts;
        if (ch == NCH - 1) {
            u = 1.f;                             // beta_{T-1}
            if (w == 0) bp[(size_t)(T_ - 1) * S_ + lane] = 1.f;
            rcpS = 1.f / 64.f;
            ts = T_ - 2;
        } else {
            ts = whi + 31;                       // 31 warm-up steps
            u = 1.f;                             // proxy beta at ts+1
            rcpS = 1.f / 64.f;
        }
        float ec = emb[(size_t)(ts + 1) * S_ + lane];
        float e1 = emb[(size_t)ts * S_ + lane];
        float e2 = emb[(size_t)(ts - 1) * S_ + lane];
        for (int t = ts; t >= tlo; t--) {
            float ev = ec + 1e-10f;              // em_eps[t+1]
            ec = e1; e1 = e2;
            int tp = t - 2 < 0 ? 0 : t - 2;
            e2 = emb[(size_t)tp * S_ + lane];
            float v = u * ev;                    // em*beta
            float p0 = 0, p1 = 0, p2 = 0, p3 = 0;
            #pragma unroll
            for (int k = 0; k < 16; k += 4) {
                p0 = fmaf(rlane(v, kbase + k    ), pt[k    ], p0);
                p1 = fmaf(rlane(v, kbase + k + 1), pt[k + 1], p1);
                p2 = fmaf(rlane(v, kbase + k + 2), pt[k + 2], p2);
                p3 = fmaf(rlane(v, kbase + k + 3), pt[k + 3], p3);
            }
            int buf = t & 1;
            part[buf][w][lane] = (p0 + p1) + (p2 + p3);
            __syncthreads();
            float tot = (part[buf][0][lane] + part[buf][1][lane]) +
                        (part[buf][2][lane] + part[buf][3][lane]);
            float un = tot * rcpS;
            u = un;
            if (t <= whi && w == (t & 3)) bp[(size_t)t * S_ + lane] = un;
            float S = rlane(wsum_dpp63(un), 63);
            rcpS = __builtin_amdgcn_rcpf(S);
        }
    }
}

// ---------------- Kernel D: gamma (in-place over alpha in d_out) + marginals
__global__ __launch_bounds__(256) void gamma_k(const float* __restrict__ beta,
                                               float* __restrict__ out) {
    int wid = threadIdx.x >> 6, lane = threadIdx.x & 63;
    int b = blockIdx.x >> 4;
    int tile = blockIdx.x & 15;
    int t0 = tile * 256 + wid * 64;
    float macc = 0.f;
    size_t base = ((size_t)b * T_ + t0) * 64 + lane;
    for (int i = 0; i < 64; i++) {
        float a  = out[base + (size_t)i * 64];
        float be = beta[((size_t)b * T_ + t0 + i) * 64 + lane];
        float p = a * be;
        float s = rlane(wsum_dpp63(p), 63);
        float g = p * __builtin_amdgcn_rcpf(fmaxf(s, 1e-37f));
        out[base + (size_t)i * 64] = g;
        macc += g;
    }
    atomicAdd(&out[MARG_OFF + b * 64 + lane], macc * (1.0f / T_));
}

extern "C" void kernel_launch(void* const* d_in, const int* in_sizes, int n_in,
                              void* d_out, int out_size, void* d_ws, size_t ws_size,
                              hipStream_t stream) {
    (void)in_sizes; (void)n_in; (void)out_size; (void)ws_size;
    const float* obs    = (const float*)d_in[0];
    const float* W1     = (const float*)d_in[1];
    const float* b1     = (const float*)d_in[2];
    const float* W2     = (const float*)d_in[3];
    const float* b2     = (const float*)d_in[4];
    const float* W3     = (const float*)d_in[5];
    const float* b3     = (const float*)d_in[6];
    const float* LT     = (const float*)d_in[7];
    const float* lip    = (const float*)d_in[8];
    const float* logr   = (const float*)d_in[9];
    const float* logitp = (const float*)d_in[10];
    float* out = (float*)d_out;
    float* ws  = (float*)d_ws;

    hipLaunchKernelGGL(prep_k, dim3(1), dim3(256), 0, stream, LT, lip, logr, logitp, ws, out);
    hipLaunchKernelGGL(mlp_k, dim3(1024), dim3(256), 0, stream,
                       obs, W1, b1, W2, b2, W3, b3, ws + EM_OFF);
    hipLaunchKernelGGL(scan_k, dim3(2 * B_ * NCH), dim3(256), 0, stream,
                       ws + EM_OFF, ws + P_OFF, ws + PT_OFF, ws + INITP_OFF,
                       out + SP_OFF, ws + BETA_OFF, out + LL_OFF);
    hipLaunchKernelGGL(gamma_k, dim3(512), dim3(256), 0, stream, ws + BETA_OFF, out);
}